// Round 8
// baseline (163.347 us; speedup 1.0000x reference)
//
#include <hip/hip_runtime.h>
#include <hip/hip_bf16.h>
#include <stdint.h>
#include <stddef.h>

#define BATCH 256
#define OC 4096
#define IC 4096
#define VALUE_SCALE 0.1f

#define BN 64           // N-tile per WG
#define BK 32           // K-step (elements)
#define KS 8            // split-K; ks = bid&7 pins K-slice to one XCD
#define KPER (IC / KS)  // 512
#define NT (KPER / BK)  // 16 K-steps
#define YSZ (BATCH * OC)

#define NBIN 256        // scatter bins: 256 x 256KB W-regions (64 pages each)
#define BINCAP 8192     // mean 3906, sigma ~62 -> +68 sigma headroom
#define BIN_ELEMS 4096  // elements per bin_k block

typedef float f32x4 __attribute__((ext_vector_type(4)));
typedef short bf16x8 __attribute__((ext_vector_type(8)));

__device__ __forceinline__ short f2bf(float f) {
    return (short)__bfloat16_as_ushort(__float2bfloat16(f));  // RNE
}

// lgkm-only barrier: never drains vmcnt -> in-flight global loads span it (T4)
__device__ __forceinline__ void barrier_nodrain() {
    asm volatile("s_waitcnt lgkmcnt(0)" ::: "memory");
    __builtin_amdgcn_sched_barrier(0);
    __builtin_amdgcn_s_barrier();
    __builtin_amdgcn_sched_barrier(0);
}

// ======================= scatter: bin by 256KB region, then replay =======================
// R1-R6 ledger: direct 1M random 4B writes ~95us (each wave touches 64 distinct 4KB
// pages -> translation-serialized). Binning gives replay blocks page locality.
__global__ void bin_k(const int* __restrict__ idx, const float* __restrict__ val, int n,
                      int* __restrict__ gcnt, int2* __restrict__ pairs) {
    __shared__ int hcnt[NBIN];
    __shared__ int hbase[NBIN];
    const int t = threadIdx.x;
    for (int b = t; b < NBIN; b += 256) hcnt[b] = 0;
    __syncthreads();

    const int start = blockIdx.x * BIN_ELEMS;
    int mi[16]; float mv[16]; int mp[16];
#pragma unroll
    for (int e = 0; e < 16; ++e) {
        int i = start + e * 256 + t;
        if (i < n) {
            mi[e] = idx[i];
            mv[e] = val[i];
            mp[e] = atomicAdd(&hcnt[mi[e] >> 16], 1);   // LDS atomic
        }
    }
    __syncthreads();
    for (int b = t; b < NBIN; b += 256)
        if (hcnt[b] > 0) hbase[b] = atomicAdd(&gcnt[b], hcnt[b]);  // exact reservation
    __syncthreads();
#pragma unroll
    for (int e = 0; e < 16; ++e) {
        int i = start + e * 256 + t;
        if (i < n) {
            int bin = mi[e] >> 16;
            int pos = hbase[bin] + mp[e];
            if (pos < BINCAP)
                pairs[(size_t)bin * BINCAP + pos] = make_int2(mi[e], __float_as_int(mv[e]));
        }
    }
}

__global__ void replay_k(const int* __restrict__ gcnt, const int2* __restrict__ pairs,
                         float* __restrict__ w) {
    const int b = blockIdx.x;
    int cnt = gcnt[b]; if (cnt > BINCAP) cnt = BINCAP;
    for (int i = threadIdx.x; i < cnt; i += 256) {
        int2 p = pairs[(size_t)b * BINCAP + i];
        w[p.x] = __int_as_float(p.y) * VALUE_SCALE;   // dup winner arbitrary (accepted R1..R6)
    }
}

// fallback (no ws): direct scatter
__global__ void scatter_k(float* __restrict__ w, const int* __restrict__ idx,
                          const float* __restrict__ val, int n) {
    int i = blockIdx.x * blockDim.x + threadIdx.x;
    if (i < n) w[idx[i]] = val[i] * VALUE_SCALE;
}

// ======================= split-K bf16 GEMM, register-staged =======================
// R6 post-mortem: global_load_lds staging ran ~7100cy/step (~10 DMA loads/wave,
// latency-serialized -> per-wave outstanding-depth-limit hypothesis). Reg-stage
// instead: global_load_dwordx4 -> cvt bf16 in regs -> ds_write_b128. LDS 40KB/WG
// (bf16), zero cvt in the MFMA phase. lgkm-only barriers: the 10 in-flight loads
// for step t+1 span both barriers; vmcnt wait lands at first ra/rb use (write_lds).
// Race ledger: reads of buf b drain (lgkm0) before barrier1(t-1) < write_lds(b)@t;
// writes drain before barrier2(t) < compute(b)@t+1.
// Swizzle: 8-elem chunk cs' = cs ^ ((row>>1)&3), both write and read sides.
__global__ __launch_bounds__(256) void gemm_k(const float* __restrict__ x,
                                              const float* __restrict__ w,
                                              float* __restrict__ part,
                                              float* __restrict__ y) {
    const int tid  = threadIdx.x;
    const int lane = tid & 63;
    const int wv   = tid >> 6;      // 0..3 -> A rows wv*64..+64
    const int bid  = blockIdx.x;
    const int ks   = bid & 7;
    const int bn   = bid >> 3;
    const int k0   = ks * KPER;
    const int nc0  = bn * BN;

    __shared__ __align__(16) short At[2][BATCH * BK];  // 2 x 16KB bf16
    __shared__ __align__(16) short Bt[2][BN * BK];     // 2 x 4KB  -> 40KB total

    f32x4 acc[4][4];
#pragma unroll
    for (int m = 0; m < 4; ++m)
#pragma unroll
        for (int n = 0; n < 4; ++n) acc[m][n] = (f32x4)0.0f;

    f32x4 ra[8];   // A in-flight: 4 rows x 8 floats
    f32x4 rb[2];   // B in-flight: 1 row x 8 floats

    const int rsub = lane >> 2;     // 0..15: row within 16-row group
    const int csl  = lane & 3;      // 8-float k-chunk 0..3

    auto load_regs = [&](int t) {
        const int kg = k0 + t * BK + csl * 8;
#pragma unroll
        for (int j = 0; j < 4; ++j) {            // A rows wv*64 + j*16 + rsub
            const float* s = x + (size_t)(wv * 64 + j * 16 + rsub) * IC + kg;
            ra[2 * j]     = *(const f32x4*)s;
            ra[2 * j + 1] = *(const f32x4*)(s + 4);
        }
        {                                        // B row nc0 + wv*16 + rsub
            const float* s = w + (size_t)(nc0 + wv * 16 + rsub) * IC + kg;
            rb[0] = *(const f32x4*)s;
            rb[1] = *(const f32x4*)(s + 4);
        }
    };

    // pack 8 fp32 -> 8 consecutive bf16 (one 16B chunk), store swizzled
    auto write_lds = [&](int buf) {
#pragma unroll
        for (int j = 0; j < 4; ++j) {
            int row = wv * 64 + j * 16 + rsub;
            bf16x8 v;
#pragma unroll
            for (int q = 0; q < 4; ++q) { v[q] = f2bf(ra[2 * j][q]); v[q + 4] = f2bf(ra[2 * j + 1][q]); }
            int csw = csl ^ ((row >> 1) & 3);
            *(bf16x8*)&At[buf][row * BK + csw * 8] = v;
        }
        {
            int row = wv * 16 + rsub;
            bf16x8 v;
#pragma unroll
            for (int q = 0; q < 4; ++q) { v[q] = f2bf(rb[0][q]); v[q + 4] = f2bf(rb[1][q]); }
            int csw = csl ^ ((row >> 1) & 3);
            *(bf16x8*)&Bt[buf][row * BK + csw * 8] = v;
        }
    };

    auto compute = [&](int buf) {
        bf16x8 a[4], b[4];
        const int cs = lane >> 4;                // frag k-chunk: k = cs*8 + j (proven map)
#pragma unroll
        for (int m = 0; m < 4; ++m) {
            int row = wv * 64 + m * 16 + (lane & 15);
            a[m] = *(const bf16x8*)&At[buf][row * BK + (cs ^ ((row >> 1) & 3)) * 8];
        }
#pragma unroll
        for (int n = 0; n < 4; ++n) {
            int row = n * 16 + (lane & 15);
            b[n] = *(const bf16x8*)&Bt[buf][row * BK + (cs ^ ((row >> 1) & 3)) * 8];
        }
#pragma unroll
        for (int n = 0; n < 4; ++n)
#pragma unroll
            for (int m = 0; m < 4; ++m)
                acc[m][n] = __builtin_amdgcn_mfma_f32_16x16x32_bf16(a[m], b[n], acc[m][n], 0, 0, 0);
    };

    // prologue
    load_regs(0);
    write_lds(0);
    barrier_nodrain();

    for (int t = 0; t < NT; ++t) {
        const int cur = t & 1;
        if (t + 1 < NT) load_regs(t + 1);   // 10 VMEM stay in flight across barriers
        compute(cur);
        barrier_nodrain();                  // all reads of buf[cur] drained
        if (t + 1 < NT) {
            write_lds(cur ^ 1);             // vmcnt wait at first ra/rb use
            barrier_nodrain();              // writes visible for next compute
        }
    }

    // epilogue: C/D layout col=lane&15, row=(lane>>4)*4+reg  [proven R1..R6]
    if (part) {
        float* dst = part + (size_t)ks * YSZ;
#pragma unroll
        for (int m = 0; m < 4; ++m) {
            int r0 = wv * 64 + m * 16 + (lane >> 4) * 4;
#pragma unroll
            for (int n = 0; n < 4; ++n) {
                int c = nc0 + n * 16 + (lane & 15);
#pragma unroll
                for (int r = 0; r < 4; ++r)
                    dst[(size_t)(r0 + r) * OC + c] = acc[m][n][r];
            }
        }
    } else {
#pragma unroll
        for (int m = 0; m < 4; ++m) {
            int r0 = wv * 64 + m * 16 + (lane >> 4) * 4;
#pragma unroll
            for (int n = 0; n < 4; ++n) {
                int c = nc0 + n * 16 + (lane & 15);
#pragma unroll
                for (int r = 0; r < 4; ++r)
                    atomicAdd(&y[(size_t)(r0 + r) * OC + c], acc[m][n][r]);
            }
        }
    }
}

__global__ void reduce_k(const float* __restrict__ part, float* __restrict__ y) {
    int i = (blockIdx.x * blockDim.x + threadIdx.x) * 4;
    f32x4 s = *(const f32x4*)(part + i);
#pragma unroll
    for (int p = 1; p < KS; ++p) s += *(const f32x4*)(part + (size_t)p * YSZ + i);
    *(f32x4*)(y + i) = s;
}

extern "C" void kernel_launch(void* const* d_in, const int* in_sizes, int n_in,
                              void* d_out, int out_size, void* d_ws, size_t ws_size,
                              hipStream_t stream) {
    const float* x  = (const float*)d_in[0];
    float*       w  = (float*)d_in[1];      // scattered in place (set = idempotent)
    const int*   fi = (const int*)d_in[2];
    const float* fv = (const float*)d_in[3];
    float*       y  = (float*)d_out;
    const int nflip = in_sizes[2];

    const bool use_ws = ws_size >= (size_t)KS * YSZ * sizeof(float);  // 32MB (taken, R4/R6)
    float* part = use_ws ? (float*)d_ws : nullptr;

    if (use_ws) {
        int*  gcnt  = (int*)d_ws;                      // [0, 1KB)
        int2* pairs = (int2*)((char*)d_ws + 4096);     // 16MB; reused by part afterwards
        hipMemsetAsync(gcnt, 0, NBIN * sizeof(int), stream);
        bin_k<<<dim3((nflip + BIN_ELEMS - 1) / BIN_ELEMS), dim3(256), 0, stream>>>(fi, fv, nflip, gcnt, pairs);
        replay_k<<<dim3(NBIN), dim3(256), 0, stream>>>(gcnt, pairs, w);
    } else {
        hipMemsetAsync(d_out, 0, (size_t)out_size * sizeof(float), stream);
        scatter_k<<<dim3((nflip + 255) / 256), dim3(256), 0, stream>>>(w, fi, fv, nflip);
    }
    gemm_k<<<dim3((OC / BN) * KS), dim3(256), 0, stream>>>(x, w, part, y);
    if (use_ws)
        reduce_k<<<dim3(YSZ / (4 * 256)), dim3(256), 0, stream>>>(part, y);
}